// Round 15
// baseline (440.673 us; speedup 1.0000x reference)
//
#include <hip/hip_runtime.h>
#include <hip/hip_bf16.h>

// Problem dims
#define D_IN  1024
#define HID   256
#define OUT_D 128

using bf16x8  = __attribute__((ext_vector_type(8))) short;
using bf16x4  = __attribute__((ext_vector_type(4))) short;
using f32x4   = __attribute__((ext_vector_type(4))) float;
typedef unsigned int u32;

__device__ inline float bf2f(short s) {
    unsigned u = ((unsigned)(unsigned short)s) << 16;
    return __uint_as_float(u);
}
__device__ inline short f2bf(float f) {
    __hip_bfloat16 h = __float2bfloat16(f);   // RNE
    return *reinterpret_cast<short*>(&h);
}

// async global->LDS, 16 B per lane (HW: wave-uniform LDS base + lane*16)
__device__ __forceinline__ void gld16(void* lds, const void* g) {
    __builtin_amdgcn_global_load_lds(
        (const __attribute__((address_space(1))) u32*)g,
        (__attribute__((address_space(3))) u32*)lds, 16, 0, 0);
}

// ---------------------------------------------------------------------------
// pack_all: all 8 weight transposes (f32 [K][N] -> bf16 [n][K]) + bias concat
// ---------------------------------------------------------------------------
__global__ void pack_all(
    const float* __restrict__ W_ui, const float* __restrict__ W_dm,
    const float* __restrict__ W_di, const float* __restrict__ W_um,
    const float* __restrict__ W_uu, const float* __restrict__ W_du,
    const float* __restrict__ W_up, const float* __restrict__ W_dp,
    const float* __restrict__ b_ui, const float* __restrict__ b_dm,
    const float* __restrict__ b_di, const float* __restrict__ b_um,
    short* __restrict__ Wut, short* __restrict__ Wdt,
    short* __restrict__ Wuut, short* __restrict__ Wdut,
    short* __restrict__ Wupt, short* __restrict__ Wdpt,
    float* __restrict__ bu, float* __restrict__ bd)
{
    const int z = blockIdx.z;
    const int tx = threadIdx.x, ty = threadIdx.y;
    if (z == 8) {  // biases
        if (blockIdx.x != 0 || blockIdx.y != 0) return;
        int t = ty * 32 + tx;  // 0..255
        bu[t] = b_ui[t]; bu[256 + t] = b_dm[t];
        bd[t] = b_di[t]; bd[256 + t] = b_um[t];
        return;
    }
    const float* in; short* out; int K, N, n_off = 0;
    switch (z) {
        case 0: in = W_ui; out = Wut;  K = 1024; N = 256; n_off = 0;   break;
        case 1: in = W_dm; out = Wut;  K = 1024; N = 256; n_off = 256; break;
        case 2: in = W_di; out = Wdt;  K = 1024; N = 256; n_off = 0;   break;
        case 3: in = W_um; out = Wdt;  K = 1024; N = 256; n_off = 256; break;
        case 4: in = W_uu; out = Wuut; K = 256;  N = 256; break;
        case 5: in = W_du; out = Wdut; K = 256;  N = 256; break;
        case 6: in = W_up; out = Wupt; K = 256;  N = 128; break;
        default:in = W_dp; out = Wdpt; K = 256;  N = 128; break;
    }
    const int n0 = blockIdx.x * 32, k0 = blockIdx.y * 32;
    if (n0 >= N || k0 >= K) return;
    __shared__ float t[32][33];
#pragma unroll
    for (int j = 0; j < 32; j += 8)
        t[ty + j][tx] = in[(size_t)(k0 + ty + j) * N + (n0 + tx)];
    __syncthreads();
#pragma unroll
    for (int j = 0; j < 32; j += 8)
        out[(size_t)(n_off + n0 + ty + j) * K + (k0 + tx)] = f2bf(t[tx][ty + j]);
}

// ---------------------------------------------------------------------------
// Dual MFMA GEMM, R12-proven single-buffer 2-phase structure, widened N-tile.
//   BM=128, BN = BN256 ? 256 : 128, BK=32, 256 thr (4 waves).
//   BN256: waves 2M x 2N, per-wave 64x128 (acc 4x8 frags); raises arithmetic
//   intensity through the STAGING path to 65 FLOP/B (vs 43.7 at BN=128) --
//   R14 post-mortem showed staging-byte BW (~13 B/cy/CU through L2/L3/HBM)
//   is the binding constraint, not scheduling.
//   Per K-step: stage (gld16, linear dest + pre-swizzled source, rule #21)
//   | __syncthreads | MFMA | __syncthreads.
//   Two independent GEMMs arg-muxed by block range (small fills big's tail).
//   Bijective XCD chunk swizzle per sub-grid, n-fastest.
// ---------------------------------------------------------------------------
template <bool RELU, bool AF32, bool CF32, bool BN256>
__global__ __launch_bounds__(256) void mfma_gemm2(
    const void* __restrict__ A0_, int lda0, const short* __restrict__ Wt0,
    const float* __restrict__ bias0, void* __restrict__ C0,
    int M0, int N0, int K0, int nN0, int nb0,
    const void* __restrict__ A1_, int lda1, const short* __restrict__ Wt1,
    const float* __restrict__ bias1, void* __restrict__ C1,
    int M1, int N1, int K1, int nN1)
{
    constexpr int BN = BN256 ? 256 : 128;
    constexpr int NJ = BN256 ? 8 : 4;             // B frags per wave
    constexpr int ABYTES = AF32 ? 16384 : 8192;   // 128 rows x 128B / 64B
    constexpr int BBYTES = BN * 64;               // BN rows x 64B
    __shared__ __align__(16) char smem[ABYTES + BBYTES];
    char* As = smem;
    char* Bs = smem + ABYTES;

    const int tid = threadIdx.x;

    // select GEMM by block range
    const void* A_; const short* Wt; const float* bias; void* Cv;
    int lda, M, N, K, nN, nwg, orig;
    if ((int)blockIdx.x < nb0) {
        A_ = A0_; lda = lda0; Wt = Wt0; bias = bias0; Cv = C0;
        M = M0; N = N0; K = K0; nN = nN0; nwg = nb0; orig = blockIdx.x;
    } else {
        A_ = A1_; lda = lda1; Wt = Wt1; bias = bias1; Cv = C1;
        M = M1; N = N1; K = K1; nN = nN1;
        nwg = gridDim.x - nb0; orig = blockIdx.x - nb0;
    }

    // bijective XCD chunk swizzle (m204) within the sub-grid
    const int qq = nwg >> 3, rr = nwg & 7;
    const int xcd = orig & 7, pos = orig >> 3;
    const int wg = (xcd < rr) ? (xcd * (qq + 1) + pos)
                              : (rr * (qq + 1) + (xcd - rr) * qq + pos);
    const int n0 = (wg % nN) * BN;
    const int m0 = (wg / nN) * 128;

    const int w = tid >> 6, l = tid & 63;
    const int wm = (w >> 1) * 64;
    const int wn = (w & 1) * (BN / 2);
    const int fr = l & 15, fg = l >> 4;

    f32x4 acc[4][NJ] = {};

    const char* Ab = (const char*)A_;
    const char* Bb = (const char*)Wt;
    const size_t lda_b = (size_t)lda * (AF32 ? 4 : 2);
    const size_t ldb_b = (size_t)K * 2;

    for (int k0 = 0; k0 < K; k0 += 32) {
        // ---- stage A (128 rows x BK=32) ----
        if constexpr (AF32) {
#pragma unroll
            for (int i = 0; i < 4; ++i) {      // 128 rows x 128B f32
                int o = i * 4096 + tid * 16;
                int row = o >> 7, cb = o & 127;
                int scb = cb ^ ((row & 7) << 4);
                int arow = m0 + row; if (arow > M - 1) arow = M - 1;
                gld16(As + o, Ab + (size_t)arow * lda_b + (size_t)k0 * 4 + scb);
            }
        } else {
#pragma unroll
            for (int i = 0; i < 2; ++i) {      // 128 rows x 64B bf16
                int o = i * 4096 + tid * 16;
                int row = o >> 6, cb = o & 63;
                int scb = cb ^ ((row & 3) << 4);
                int arow = m0 + row; if (arow > M - 1) arow = M - 1;
                gld16(As + o, Ab + (size_t)arow * lda_b + (size_t)k0 * 2 + scb);
            }
        }
        // ---- stage B (BN rows x 64B bf16) ----
#pragma unroll
        for (int i = 0; i < BBYTES / 4096; ++i) {
            int o = i * 4096 + tid * 16;
            int row = o >> 6, cb = o & 63;
            int scb = cb ^ ((row & 3) << 4);
            gld16(Bs + o, Bb + (size_t)(n0 + row) * ldb_b + (size_t)k0 * 2 + scb);
        }
        __syncthreads();   // drains vmcnt; tile ready

        bf16x8 af[4], bfv[NJ];
#pragma unroll
        for (int i = 0; i < 4; ++i) {
            int row = wm + i * 16 + fr;
            if constexpr (AF32) {
                int sw = (row & 7) << 4;
                const char* rb = As + row * 128;
                f32x4 lo = *reinterpret_cast<const f32x4*>(rb + ((fg * 32) ^ sw));
                f32x4 hi = *reinterpret_cast<const f32x4*>(rb + ((fg * 32 + 16) ^ sw));
                bf16x8 t;
                t[0] = f2bf(lo[0]); t[1] = f2bf(lo[1]);
                t[2] = f2bf(lo[2]); t[3] = f2bf(lo[3]);
                t[4] = f2bf(hi[0]); t[5] = f2bf(hi[1]);
                t[6] = f2bf(hi[2]); t[7] = f2bf(hi[3]);
                af[i] = t;
            } else {
                int cb = (fg * 16) ^ ((row & 3) << 4);
                af[i] = *reinterpret_cast<const bf16x8*>(As + row * 64 + cb);
            }
        }
#pragma unroll
        for (int j = 0; j < NJ; ++j) {
            int row = wn + j * 16 + fr;
            int cb = (fg * 16) ^ ((row & 3) << 4);
            bfv[j] = *reinterpret_cast<const bf16x8*>(Bs + row * 64 + cb);
        }
#pragma unroll
        for (int i = 0; i < 4; ++i)
#pragma unroll
            for (int j = 0; j < NJ; ++j)
                acc[i][j] = __builtin_amdgcn_mfma_f32_16x16x32_bf16(
                    af[i], bfv[j], acc[i][j], 0, 0, 0);

        __syncthreads();   // reads done; next stage may overwrite
    }

    // epilogue: C/D layout col=lane&15, row=(lane>>4)*4+reg  [m89-verified]
#pragma unroll
    for (int i = 0; i < 4; ++i) {
#pragma unroll
        for (int e = 0; e < 4; ++e) {
            int gm = m0 + wm + i * 16 + fg * 4 + e;
            if (gm >= M) continue;
#pragma unroll
            for (int j = 0; j < NJ; ++j) {
                int gn = n0 + wn + j * 16 + fr;
                float v = acc[i][j][e] + bias[gn];
                if (RELU) v = fmaxf(v, 0.f);
                if (CF32) ((float*)Cv)[(size_t)gm * N + gn] = v;
                else      ((short*)Cv)[(size_t)gm * N + gn] = f2bf(v);
            }
        }
    }
}

// ---------------------------------------------------------------------------
// CSR construction, fused: one hist, one scan (2 blocks), one fill
// ---------------------------------------------------------------------------
__global__ void hist2(const int* __restrict__ eu, const int* __restrict__ ed,
                      int* __restrict__ cu, int* __restrict__ cd, int E)
{
    int i = blockIdx.x * blockDim.x + threadIdx.x;
    if (i < E) atomicAdd(&cu[eu[i]], 1);
    else if (i < 2 * E) atomicAdd(&cd[ed[i - E]], 1);
}

__global__ __launch_bounds__(1024) void scan2(
    const int* __restrict__ cnt_u, int* __restrict__ offs_u, int U,
    const int* __restrict__ cnt_d, int* __restrict__ offs_d, int D)
{
    const int* cnt = (blockIdx.x == 0) ? cnt_u : cnt_d;
    int* offs      = (blockIdx.x == 0) ? offs_u : offs_d;
    const int n    = (blockIdx.x == 0) ? U : D;

    __shared__ int tsum[1024];
    const int t = threadIdx.x;
    const int chunk = (n + 1023) / 1024;
    const int lo = t * chunk;
    const int hi = min(lo + chunk, n);
    int s = 0;
    for (int i = lo; i < hi; ++i) s += cnt[i];
    tsum[t] = s;
    __syncthreads();
    for (int d = 1; d < 1024; d <<= 1) {
        int v = (t >= d) ? tsum[t - d] : 0;
        __syncthreads();
        tsum[t] += v;
        __syncthreads();
    }
    int run = (t > 0) ? tsum[t - 1] : 0;
    for (int i = lo; i < hi; ++i) {
        offs[i] = run;
        run += cnt[i];
    }
}

// mutates offs -> segment END; srclist grouped by dst
__global__ void fill2(const int* __restrict__ eu, const int* __restrict__ ed,
                      int* __restrict__ offs_u, int* __restrict__ srcl_u,
                      int* __restrict__ offs_d, int* __restrict__ srcl_d, int E)
{
    int i = blockIdx.x * blockDim.x + threadIdx.x;
    if (i < E) {
        int p = atomicAdd(&offs_u[eu[i]], 1);
        srcl_u[p] = ed[i];
    } else if (i < 2 * E) {
        int k = i - E;
        int p = atomicAdd(&offs_d[ed[k]], 1);
        srcl_d[p] = eu[k];
    }
}

// ---------------------------------------------------------------------------
// Segment sum, both directions in one launch; 1 wave/row, 4-deep gather unroll
// ---------------------------------------------------------------------------
__global__ __launch_bounds__(256) void seg_sum_both(
    const short* __restrict__ dish_msg, const short* __restrict__ user_msg,
    const int* __restrict__ srcl_u, const int* __restrict__ offs_u,
    const int* __restrict__ cnt_u,
    const int* __restrict__ srcl_d, const int* __restrict__ offs_d,
    const int* __restrict__ cnt_d,
    short* __restrict__ user_buf, short* __restrict__ dish_buf,
    int U, int D, int nbU)
{
    const short* msg; const int *sl, *oe, *ct; short* acc; int nRows, rb;
    if (blockIdx.x < nbU) {
        msg = dish_msg; sl = srcl_u; oe = offs_u; ct = cnt_u;
        acc = user_buf; nRows = U; rb = blockIdx.x;
    } else {
        msg = user_msg; sl = srcl_d; oe = offs_d; ct = cnt_d;
        acc = dish_buf; nRows = D; rb = blockIdx.x - nbU;
    }
    int row = rb * 4 + (threadIdx.x >> 6);
    if (row >= nRows) return;
    const int lane = threadIdx.x & 63;
    const int deg = ct[row];
    if (deg == 0) return;
    const int base = oe[row] - deg;

    float s0 = 0.f, s1 = 0.f, s2 = 0.f, s3 = 0.f;
    int j = 0;
    for (; j + 4 <= deg; j += 4) {
        int i0 = sl[base + j], i1 = sl[base + j + 1];
        int i2 = sl[base + j + 2], i3 = sl[base + j + 3];
        bf16x4 v0 = *(const bf16x4*)&msg[(size_t)i0 * 512 + lane * 4];
        bf16x4 v1 = *(const bf16x4*)&msg[(size_t)i1 * 512 + lane * 4];
        bf16x4 v2 = *(const bf16x4*)&msg[(size_t)i2 * 512 + lane * 4];
        bf16x4 v3 = *(const bf16x4*)&msg[(size_t)i3 * 512 + lane * 4];
        s0 += bf2f(v0[0]) + bf2f(v1[0]) + bf2f(v2[0]) + bf2f(v3[0]);
        s1 += bf2f(v0[1]) + bf2f(v1[1]) + bf2f(v2[1]) + bf2f(v3[1]);
        s2 += bf2f(v0[2]) + bf2f(v1[2]) + bf2f(v2[2]) + bf2f(v3[2]);
        s3 += bf2f(v0[3]) + bf2f(v1[3]) + bf2f(v2[3]) + bf2f(v3[3]);
    }
    for (; j < deg; ++j) {
        int i0 = sl[base + j];
        bf16x4 v = *(const bf16x4*)&msg[(size_t)i0 * 512 + lane * 4];
        s0 += bf2f(v[0]); s1 += bf2f(v[1]); s2 += bf2f(v[2]); s3 += bf2f(v[3]);
    }
    bf16x4 c = *(bf16x4*)&acc[(size_t)row * 512 + lane * 4];
    c[0] = f2bf(bf2f(c[0]) + s0);
    c[1] = f2bf(bf2f(c[1]) + s1);
    c[2] = f2bf(bf2f(c[2]) + s2);
    c[3] = f2bf(bf2f(c[3]) + s3);
    *(bf16x4*)&acc[(size_t)row * 512 + lane * 4] = c;
}

extern "C" void kernel_launch(void* const* d_in, const int* in_sizes, int n_in,
                              void* d_out, int out_size, void* d_ws, size_t ws_size,
                              hipStream_t stream)
{
    const float* user_feat = (const float*)d_in[0];
    const float* dish_feat = (const float*)d_in[1];
    const int*   edge_user = (const int*)d_in[2];
    const int*   edge_dish = (const int*)d_in[3];
    const float* W_ui = (const float*)d_in[4];  const float* b_ui = (const float*)d_in[5];
    const float* W_di = (const float*)d_in[6];  const float* b_di = (const float*)d_in[7];
    const float* W_um = (const float*)d_in[8];  const float* b_um = (const float*)d_in[9];
    const float* W_dm = (const float*)d_in[10]; const float* b_dm = (const float*)d_in[11];
    const float* W_uu = (const float*)d_in[12]; const float* b_uu = (const float*)d_in[13];
    const float* W_du = (const float*)d_in[14]; const float* b_du = (const float*)d_in[15];
    const float* W_up = (const float*)d_in[16]; const float* b_up = (const float*)d_in[17];
    const float* W_dp = (const float*)d_in[18]; const float* b_dp = (const float*)d_in[19];

    const int U = in_sizes[0] / D_IN;   // 50000
    const int D = in_sizes[1] / D_IN;   // 10000
    const int E = in_sizes[2];          // 200000

    float* out = (float*)d_out;
    float* user_emb = out;
    float* dish_emb = out + (size_t)U * OUT_D;

    // ---- workspace layout (shorts) ----
    short* sws = (short*)d_ws;
    short* user_buf = sws;                                  // [U][512]: init | msg
    short* dish_buf = user_buf + (size_t)U * 512;           // [D][512]
    short* user_upd = dish_buf + (size_t)D * 512;           // [U][256]
    short* dish_upd = user_upd + (size_t)U * 256;           // [D][256]
    short* Wut  = dish_upd + (size_t)D * 256;               // [512][1024]
    short* Wdt  = Wut  + (size_t)512 * 1024;                // [512][1024]
    short* Wuut = Wdt  + (size_t)512 * 1024;                // [256][256]
    short* Wdut = Wuut + (size_t)256 * 256;                 // [256][256]
    short* Wupt = Wdut + (size_t)256 * 256;                 // [128][256]
    short* Wdpt = Wupt + (size_t)128 * 256;                 // [128][256]
    float* bu   = (float*)(Wdpt + (size_t)128 * 256);       // [512]
    float* bd   = bu + 512;                                 // [512]
    int*   cnt_u  = (int*)(bd + 512);                       // [U]  \ contiguous for
    int*   cnt_d  = cnt_u + U;                              // [D]  / single memset
    int*   offs_u = cnt_d + D;                              // [U]
    int*   offs_d = offs_u + U;                             // [D]
    int*   srcl_u = offs_d + D;                             // [E]
    int*   srcl_d = srcl_u + E;                             // [E]

    // ---- 1: pack all weights + biases ----
    hipLaunchKernelGGL(pack_all, dim3(8, 32, 9), dim3(32, 8), 0, stream,
                       W_ui, W_dm, W_di, W_um, W_uu, W_du, W_up, W_dp,
                       b_ui, b_dm, b_di, b_um,
                       Wut, Wdt, Wuut, Wdut, Wupt, Wdpt, bu, bd);

    // ---- 2-5: CSR build ----
    hipMemsetAsync(cnt_u, 0, (size_t)(U + D) * sizeof(int), stream);
    int eg2 = (2 * E + 255) / 256;
    hipLaunchKernelGGL(hist2, dim3(eg2), dim3(256), 0, stream,
                       edge_user, edge_dish, cnt_u, cnt_d, E);
    hipLaunchKernelGGL(scan2, dim3(2), dim3(1024), 0, stream,
                       cnt_u, offs_u, U, cnt_d, offs_d, D);
    hipLaunchKernelGGL(fill2, dim3(eg2), dim3(256), 0, stream,
                       edge_user, edge_dish, offs_u, srcl_u, offs_d, srcl_d, E);

    const int nbU128 = (U + 127) / 128;   // 391
    const int nbD128 = (D + 127) / 128;   // 79

    // ---- 6: BOTH big fused projections in one launch (f32 A, BN=256, nN=2)
    {
        int nb0 = nbU128 * 2, nb1 = nbD128 * 2;
        hipLaunchKernelGGL((mfma_gemm2<true, true, false, true>),
                           dim3(nb0 + nb1), dim3(256), 0, stream,
                           user_feat, D_IN, Wut, bu, user_buf, U, 512, D_IN, 2, nb0,
                           dish_feat, D_IN, Wdt, bd, dish_buf, D, 512, D_IN, 2);
    }

    // ---- 7: aggregation, both directions ----
    int nbU = (U + 3) / 4;
    hipLaunchKernelGGL(seg_sum_both, dim3(nbU + (D + 3) / 4), dim3(256), 0, stream,
                       dish_buf + HID, user_buf + HID,
                       srcl_u, offs_u, cnt_u, srcl_d, offs_d, cnt_d,
                       user_buf, dish_buf, U, D, nbU);

    // ---- 8: BOTH updates in one launch (bf16 A, lda=512, BN=256, nN=1) ----
    {
        int nb0 = nbU128, nb1 = nbD128;
        hipLaunchKernelGGL((mfma_gemm2<true, false, false, true>),
                           dim3(nb0 + nb1), dim3(256), 0, stream,
                           user_buf, 512, Wuut, b_uu, user_upd, U, HID, HID, 1, nb0,
                           dish_buf, 512, Wdut, b_du, dish_upd, D, HID, HID, 1);
    }

    // ---- 9: BOTH final projections in one launch (f32 out, BN=128) ----
    {
        int nb0 = nbU128, nb1 = nbD128;
        hipLaunchKernelGGL((mfma_gemm2<false, false, true, false>),
                           dim3(nb0 + nb1), dim3(256), 0, stream,
                           user_upd, HID, Wupt, b_up, user_emb, U, OUT_D, HID, 1, nb0,
                           dish_upd, HID, Wdpt, b_dp, dish_emb, D, OUT_D, HID, 1);
    }
}

// Round 16
// 329.301 us; speedup vs baseline: 1.3382x; 1.3382x over previous
//
#include <hip/hip_runtime.h>
#include <hip/hip_bf16.h>

// Problem dims
#define D_IN  1024
#define HID   256
#define OUT_D 128

using bf16x8  = __attribute__((ext_vector_type(8))) short;
using bf16x4  = __attribute__((ext_vector_type(4))) short;
using f32x4   = __attribute__((ext_vector_type(4))) float;
typedef unsigned int u32;

__device__ inline float bf2f(short s) {
    unsigned u = ((unsigned)(unsigned short)s) << 16;
    return __uint_as_float(u);
}
__device__ inline short f2bf(float f) {
    __hip_bfloat16 h = __float2bfloat16(f);   // RNE
    return *reinterpret_cast<short*>(&h);
}

// async global->LDS, 16 B per lane (HW: wave-uniform LDS base + lane*16)
__device__ __forceinline__ void gld16(void* lds, const void* g) {
    __builtin_amdgcn_global_load_lds(
        (const __attribute__((address_space(1))) u32*)g,
        (__attribute__((address_space(3))) u32*)lds, 16, 0, 0);
}

// ---------------------------------------------------------------------------
// pack_all: all 8 weight transposes (f32 [K][N] -> bf16 [n][K]) + bias concat
// ---------------------------------------------------------------------------
__global__ void pack_all(
    const float* __restrict__ W_ui, const float* __restrict__ W_dm,
    const float* __restrict__ W_di, const float* __restrict__ W_um,
    const float* __restrict__ W_uu, const float* __restrict__ W_du,
    const float* __restrict__ W_up, const float* __restrict__ W_dp,
    const float* __restrict__ b_ui, const float* __restrict__ b_dm,
    const float* __restrict__ b_di, const float* __restrict__ b_um,
    short* __restrict__ Wut, short* __restrict__ Wdt,
    short* __restrict__ Wuut, short* __restrict__ Wdut,
    short* __restrict__ Wupt, short* __restrict__ Wdpt,
    float* __restrict__ bu, float* __restrict__ bd)
{
    const int z = blockIdx.z;
    const int tx = threadIdx.x, ty = threadIdx.y;
    if (z == 8) {  // biases
        if (blockIdx.x != 0 || blockIdx.y != 0) return;
        int t = ty * 32 + tx;  // 0..255
        bu[t] = b_ui[t]; bu[256 + t] = b_dm[t];
        bd[t] = b_di[t]; bd[256 + t] = b_um[t];
        return;
    }
    const float* in; short* out; int K, N, n_off = 0;
    switch (z) {
        case 0: in = W_ui; out = Wut;  K = 1024; N = 256; n_off = 0;   break;
        case 1: in = W_dm; out = Wut;  K = 1024; N = 256; n_off = 256; break;
        case 2: in = W_di; out = Wdt;  K = 1024; N = 256; n_off = 0;   break;
        case 3: in = W_um; out = Wdt;  K = 1024; N = 256; n_off = 256; break;
        case 4: in = W_uu; out = Wuut; K = 256;  N = 256; break;
        case 5: in = W_du; out = Wdut; K = 256;  N = 256; break;
        case 6: in = W_up; out = Wupt; K = 256;  N = 128; break;
        default:in = W_dp; out = Wdpt; K = 256;  N = 128; break;
    }
    const int n0 = blockIdx.x * 32, k0 = blockIdx.y * 32;
    if (n0 >= N || k0 >= K) return;
    __shared__ float t[32][33];
#pragma unroll
    for (int j = 0; j < 32; j += 8)
        t[ty + j][tx] = in[(size_t)(k0 + ty + j) * N + (n0 + tx)];
    __syncthreads();
#pragma unroll
    for (int j = 0; j < 32; j += 8)
        out[(size_t)(n_off + n0 + ty + j) * K + (k0 + tx)] = f2bf(t[tx][ty + j]);
}

// ---------------------------------------------------------------------------
// Dual MFMA GEMM, best-measured config: BK=64 single-buffer 2-phase
// (R4/R5-verified swizzle layout) + R12's dual-launch tail filling.
//   BM=BN=128, 256 thr (4 waves 2x2), v_mfma_f32_16x16x32_bf16.
//   Per K-step: stage (8+4 or 4+4 gld16, linear dest + pre-swizzled source,
//   rule #21) | __syncthreads | 2x16 MFMA | __syncthreads.
//   A-f32 rows 256B (swz (row&7)<<4), A-bf16/B rows 128B (swz (row&7)<<4) --
//   conflict-free family (R11-verified).
//   LDS: f32-A 48KB -> 3 blk/CU; bf16-A 32KB -> 5 blk/CU.
//   Bijective XCD chunk swizzle per sub-grid, n-fastest.
// ---------------------------------------------------------------------------
template <bool RELU, bool AF32, bool CF32>
__global__ __launch_bounds__(256) void mfma_gemm2(
    const void* __restrict__ A0_, int lda0, const short* __restrict__ Wt0,
    const float* __restrict__ bias0, void* __restrict__ C0,
    int M0, int N0, int K0, int nN0, int nb0,
    const void* __restrict__ A1_, int lda1, const short* __restrict__ Wt1,
    const float* __restrict__ bias1, void* __restrict__ C1,
    int M1, int N1, int K1, int nN1)
{
    constexpr int ABYTES = AF32 ? 32768 : 16384;  // 128 rows x 256B / 128B
    constexpr int BBYTES = 16384;                 // 128 rows x 128B
    __shared__ __align__(16) char smem[ABYTES + BBYTES];
    char* As = smem;
    char* Bs = smem + ABYTES;

    const int tid = threadIdx.x;

    // select GEMM by block range
    const void* A_; const short* Wt; const float* bias; void* Cv;
    int lda, M, N, K, nN, nwg, orig;
    if ((int)blockIdx.x < nb0) {
        A_ = A0_; lda = lda0; Wt = Wt0; bias = bias0; Cv = C0;
        M = M0; N = N0; K = K0; nN = nN0; nwg = nb0; orig = blockIdx.x;
    } else {
        A_ = A1_; lda = lda1; Wt = Wt1; bias = bias1; Cv = C1;
        M = M1; N = N1; K = K1; nN = nN1;
        nwg = gridDim.x - nb0; orig = blockIdx.x - nb0;
    }

    // bijective XCD chunk swizzle (m204) within the sub-grid
    const int qq = nwg >> 3, rr = nwg & 7;
    const int xcd = orig & 7, pos = orig >> 3;
    const int wg = (xcd < rr) ? (xcd * (qq + 1) + pos)
                              : (rr * (qq + 1) + (xcd - rr) * qq + pos);
    const int n0 = (wg % nN) * 128;
    const int m0 = (wg / nN) * 128;

    const int w = tid >> 6, l = tid & 63;
    const int wm = (w >> 1) * 64, wn = (w & 1) * 64;
    const int fr = l & 15, fg = l >> 4;

    f32x4 acc[4][4] = {};

    const char* Ab = (const char*)A_;
    const char* Bb = (const char*)Wt;
    const size_t lda_b = (size_t)lda * (AF32 ? 4 : 2);
    const size_t ldb_b = (size_t)K * 2;

    for (int k0 = 0; k0 < K; k0 += 64) {
        // ---- stage A (128 rows x BK=64) ----
        if constexpr (AF32) {
#pragma unroll
            for (int i = 0; i < 8; ++i) {      // 256B rows
                int o = i * 4096 + tid * 16;
                int row = o >> 8, cb = o & 255;
                int scb = cb ^ ((row & 7) << 4);
                int arow = m0 + row; if (arow > M - 1) arow = M - 1;
                gld16(As + o, Ab + (size_t)arow * lda_b + (size_t)k0 * 4 + scb);
            }
        } else {
#pragma unroll
            for (int i = 0; i < 4; ++i) {      // 128B rows
                int o = i * 4096 + tid * 16;
                int row = o >> 7, cb = o & 127;
                int scb = cb ^ ((row & 7) << 4);
                int arow = m0 + row; if (arow > M - 1) arow = M - 1;
                gld16(As + o, Ab + (size_t)arow * lda_b + (size_t)k0 * 2 + scb);
            }
        }
        // ---- stage B (128 rows x 128B bf16) ----
#pragma unroll
        for (int i = 0; i < 4; ++i) {
            int o = i * 4096 + tid * 16;
            int row = o >> 7, cb = o & 127;
            int scb = cb ^ ((row & 7) << 4);
            gld16(Bs + o, Bb + (size_t)(n0 + row) * ldb_b + (size_t)k0 * 2 + scb);
        }
        __syncthreads();   // drains vmcnt; tile ready

#pragma unroll
        for (int kk = 0; kk < 2; ++kk) {
            bf16x8 af[4], bfv[4];
#pragma unroll
            for (int i = 0; i < 4; ++i) {
                int row = wm + i * 16 + fr;
                int sw = (row & 7) << 4;
                if constexpr (AF32) {
                    int cbase = kk * 128 + fg * 32;
                    const char* rb = As + row * 256;
                    f32x4 lo = *reinterpret_cast<const f32x4*>(rb + (cbase ^ sw));
                    f32x4 hi = *reinterpret_cast<const f32x4*>(rb + ((cbase + 16) ^ sw));
                    bf16x8 t;
                    t[0] = f2bf(lo[0]); t[1] = f2bf(lo[1]);
                    t[2] = f2bf(lo[2]); t[3] = f2bf(lo[3]);
                    t[4] = f2bf(hi[0]); t[5] = f2bf(hi[1]);
                    t[6] = f2bf(hi[2]); t[7] = f2bf(hi[3]);
                    af[i] = t;
                } else {
                    int cb = (kk * 64 + fg * 16) ^ sw;
                    af[i] = *reinterpret_cast<const bf16x8*>(As + row * 128 + cb);
                }
            }
#pragma unroll
            for (int j = 0; j < 4; ++j) {
                int row = wn + j * 16 + fr;
                int cb = (kk * 64 + fg * 16) ^ ((row & 7) << 4);
                bfv[j] = *reinterpret_cast<const bf16x8*>(Bs + row * 128 + cb);
            }
#pragma unroll
            for (int i = 0; i < 4; ++i)
#pragma unroll
                for (int j = 0; j < 4; ++j)
                    acc[i][j] = __builtin_amdgcn_mfma_f32_16x16x32_bf16(
                        af[i], bfv[j], acc[i][j], 0, 0, 0);
        }
        __syncthreads();   // reads done; next stage may overwrite
    }

    // epilogue: C/D layout col=lane&15, row=(lane>>4)*4+reg  [m89-verified]
#pragma unroll
    for (int i = 0; i < 4; ++i) {
#pragma unroll
        for (int e = 0; e < 4; ++e) {
            int gm = m0 + wm + i * 16 + fg * 4 + e;
            if (gm >= M) continue;
#pragma unroll
            for (int j = 0; j < 4; ++j) {
                int gn = n0 + wn + j * 16 + fr;
                float v = acc[i][j][e] + bias[gn];
                if (RELU) v = fmaxf(v, 0.f);
                if (CF32) ((float*)Cv)[(size_t)gm * N + gn] = v;
                else      ((short*)Cv)[(size_t)gm * N + gn] = f2bf(v);
            }
        }
    }
}

// ---------------------------------------------------------------------------
// CSR construction, fused: one hist, one scan (2 blocks), one fill
// ---------------------------------------------------------------------------
__global__ void hist2(const int* __restrict__ eu, const int* __restrict__ ed,
                      int* __restrict__ cu, int* __restrict__ cd, int E)
{
    int i = blockIdx.x * blockDim.x + threadIdx.x;
    if (i < E) atomicAdd(&cu[eu[i]], 1);
    else if (i < 2 * E) atomicAdd(&cd[ed[i - E]], 1);
}

__global__ __launch_bounds__(1024) void scan2(
    const int* __restrict__ cnt_u, int* __restrict__ offs_u, int U,
    const int* __restrict__ cnt_d, int* __restrict__ offs_d, int D)
{
    const int* cnt = (blockIdx.x == 0) ? cnt_u : cnt_d;
    int* offs      = (blockIdx.x == 0) ? offs_u : offs_d;
    const int n    = (blockIdx.x == 0) ? U : D;

    __shared__ int tsum[1024];
    const int t = threadIdx.x;
    const int chunk = (n + 1023) / 1024;
    const int lo = t * chunk;
    const int hi = min(lo + chunk, n);
    int s = 0;
    for (int i = lo; i < hi; ++i) s += cnt[i];
    tsum[t] = s;
    __syncthreads();
    for (int d = 1; d < 1024; d <<= 1) {
        int v = (t >= d) ? tsum[t - d] : 0;
        __syncthreads();
        tsum[t] += v;
        __syncthreads();
    }
    int run = (t > 0) ? tsum[t - 1] : 0;
    for (int i = lo; i < hi; ++i) {
        offs[i] = run;
        run += cnt[i];
    }
}

// mutates offs -> segment END; srclist grouped by dst
__global__ void fill2(const int* __restrict__ eu, const int* __restrict__ ed,
                      int* __restrict__ offs_u, int* __restrict__ srcl_u,
                      int* __restrict__ offs_d, int* __restrict__ srcl_d, int E)
{
    int i = blockIdx.x * blockDim.x + threadIdx.x;
    if (i < E) {
        int p = atomicAdd(&offs_u[eu[i]], 1);
        srcl_u[p] = ed[i];
    } else if (i < 2 * E) {
        int k = i - E;
        int p = atomicAdd(&offs_d[ed[k]], 1);
        srcl_d[p] = eu[k];
    }
}

// ---------------------------------------------------------------------------
// Segment sum, both directions; writes COMPACT [rows][256] output (cmp) so
// the update GEMM reads fully-used contiguous cache lines. All rows written
// (deg==0 -> copy of init).
// ---------------------------------------------------------------------------
__global__ __launch_bounds__(256) void seg_sum_both(
    const short* __restrict__ dish_msg, const short* __restrict__ user_msg,
    const int* __restrict__ srcl_u, const int* __restrict__ offs_u,
    const int* __restrict__ cnt_u,
    const int* __restrict__ srcl_d, const int* __restrict__ offs_d,
    const int* __restrict__ cnt_d,
    const short* __restrict__ user_init, const short* __restrict__ dish_init,
    short* __restrict__ user_cmp, short* __restrict__ dish_cmp,
    int U, int D, int nbU)
{
    const short* msg; const short* init_; const int *sl, *oe, *ct;
    short* outp; int nRows, rb;
    if (blockIdx.x < nbU) {
        msg = dish_msg; sl = srcl_u; oe = offs_u; ct = cnt_u;
        init_ = user_init; outp = user_cmp; nRows = U; rb = blockIdx.x;
    } else {
        msg = user_msg; sl = srcl_d; oe = offs_d; ct = cnt_d;
        init_ = dish_init; outp = dish_cmp; nRows = D; rb = blockIdx.x - nbU;
    }
    int row = rb * 4 + (threadIdx.x >> 6);
    if (row >= nRows) return;
    const int lane = threadIdx.x & 63;
    const int deg = ct[row];
    const int base = oe[row] - deg;

    float s0 = 0.f, s1 = 0.f, s2 = 0.f, s3 = 0.f;
    int j = 0;
    for (; j + 4 <= deg; j += 4) {
        int i0 = sl[base + j], i1 = sl[base + j + 1];
        int i2 = sl[base + j + 2], i3 = sl[base + j + 3];
        bf16x4 v0 = *(const bf16x4*)&msg[(size_t)i0 * 512 + lane * 4];
        bf16x4 v1 = *(const bf16x4*)&msg[(size_t)i1 * 512 + lane * 4];
        bf16x4 v2 = *(const bf16x4*)&msg[(size_t)i2 * 512 + lane * 4];
        bf16x4 v3 = *(const bf16x4*)&msg[(size_t)i3 * 512 + lane * 4];
        s0 += bf2f(v0[0]) + bf2f(v1[0]) + bf2f(v2[0]) + bf2f(v3[0]);
        s1 += bf2f(v0[1]) + bf2f(v1[1]) + bf2f(v2[1]) + bf2f(v3[1]);
        s2 += bf2f(v0[2]) + bf2f(v1[2]) + bf2f(v2[2]) + bf2f(v3[2]);
        s3 += bf2f(v0[3]) + bf2f(v1[3]) + bf2f(v2[3]) + bf2f(v3[3]);
    }
    for (; j < deg; ++j) {
        int i0 = sl[base + j];
        bf16x4 v = *(const bf16x4*)&msg[(size_t)i0 * 512 + lane * 4];
        s0 += bf2f(v[0]); s1 += bf2f(v[1]); s2 += bf2f(v[2]); s3 += bf2f(v[3]);
    }
    bf16x4 c = *(const bf16x4*)&init_[(size_t)row * 512 + lane * 4];
    bf16x4 o;
    o[0] = f2bf(bf2f(c[0]) + s0);
    o[1] = f2bf(bf2f(c[1]) + s1);
    o[2] = f2bf(bf2f(c[2]) + s2);
    o[3] = f2bf(bf2f(c[3]) + s3);
    *(bf16x4*)&outp[(size_t)row * 256 + lane * 4] = o;
}

extern "C" void kernel_launch(void* const* d_in, const int* in_sizes, int n_in,
                              void* d_out, int out_size, void* d_ws, size_t ws_size,
                              hipStream_t stream)
{
    const float* user_feat = (const float*)d_in[0];
    const float* dish_feat = (const float*)d_in[1];
    const int*   edge_user = (const int*)d_in[2];
    const int*   edge_dish = (const int*)d_in[3];
    const float* W_ui = (const float*)d_in[4];  const float* b_ui = (const float*)d_in[5];
    const float* W_di = (const float*)d_in[6];  const float* b_di = (const float*)d_in[7];
    const float* W_um = (const float*)d_in[8];  const float* b_um = (const float*)d_in[9];
    const float* W_dm = (const float*)d_in[10]; const float* b_dm = (const float*)d_in[11];
    const float* W_uu = (const float*)d_in[12]; const float* b_uu = (const float*)d_in[13];
    const float* W_du = (const float*)d_in[14]; const float* b_du = (const float*)d_in[15];
    const float* W_up = (const float*)d_in[16]; const float* b_up = (const float*)d_in[17];
    const float* W_dp = (const float*)d_in[18]; const float* b_dp = (const float*)d_in[19];

    const int U = in_sizes[0] / D_IN;   // 50000
    const int D = in_sizes[1] / D_IN;   // 10000
    const int E = in_sizes[2];          // 200000

    float* out = (float*)d_out;
    float* user_emb = out;
    float* dish_emb = out + (size_t)U * OUT_D;

    // ---- workspace layout (shorts) ----
    short* sws = (short*)d_ws;
    short* user_buf = sws;                                  // [U][512]: init | msg
    short* dish_buf = user_buf + (size_t)U * 512;           // [D][512]
    short* user_cmp = dish_buf + (size_t)D * 512;           // [U][256] init+agg
    short* dish_cmp = user_cmp + (size_t)U * 256;           // [D][256]
    short* user_upd = dish_cmp + (size_t)D * 256;           // [U][256]
    short* dish_upd = user_upd + (size_t)U * 256;           // [D][256]
    short* Wut  = dish_upd + (size_t)D * 256;               // [512][1024]
    short* Wdt  = Wut  + (size_t)512 * 1024;                // [512][1024]
    short* Wuut = Wdt  + (size_t)512 * 1024;                // [256][256]
    short* Wdut = Wuut + (size_t)256 * 256;                 // [256][256]
    short* Wupt = Wdut + (size_t)256 * 256;                 // [128][256]
    short* Wdpt = Wupt + (size_t)128 * 256;                 // [128][256]
    float* bu   = (float*)(Wdpt + (size_t)128 * 256);       // [512]
    float* bd   = bu + 512;                                 // [512]
    int*   cnt_u  = (int*)(bd + 512);                       // [U]  \ contiguous for
    int*   cnt_d  = cnt_u + U;                              // [D]  / single memset
    int*   offs_u = cnt_d + D;                              // [U]
    int*   offs_d = offs_u + U;                             // [D]
    int*   srcl_u = offs_d + D;                             // [E]
    int*   srcl_d = srcl_u + E;                             // [E]

    // ---- 1: pack all weights + biases ----
    hipLaunchKernelGGL(pack_all, dim3(8, 32, 9), dim3(32, 8), 0, stream,
                       W_ui, W_dm, W_di, W_um, W_uu, W_du, W_up, W_dp,
                       b_ui, b_dm, b_di, b_um,
                       Wut, Wdt, Wuut, Wdut, Wupt, Wdpt, bu, bd);

    // ---- 2-5: CSR build ----
    hipMemsetAsync(cnt_u, 0, (size_t)(U + D) * sizeof(int), stream);
    int eg2 = (2 * E + 255) / 256;
    hipLaunchKernelGGL(hist2, dim3(eg2), dim3(256), 0, stream,
                       edge_user, edge_dish, cnt_u, cnt_d, E);
    hipLaunchKernelGGL(scan2, dim3(2), dim3(1024), 0, stream,
                       cnt_u, offs_u, U, cnt_d, offs_d, D);
    hipLaunchKernelGGL(fill2, dim3(eg2), dim3(256), 0, stream,
                       edge_user, edge_dish, offs_u, srcl_u, offs_d, srcl_d, E);

    const int nbU128 = (U + 127) / 128;   // 391
    const int nbD128 = (D + 127) / 128;   // 79

    // ---- 6: BOTH big fused projections in one launch (f32 A, BK=64) ----
    {
        int nb0 = nbU128 * 4, nb1 = nbD128 * 4;
        hipLaunchKernelGGL((mfma_gemm2<true, true, false>),
                           dim3(nb0 + nb1), dim3(256), 0, stream,
                           user_feat, D_IN, Wut, bu, user_buf, U, 512, D_IN, 4, nb0,
                           dish_feat, D_IN, Wdt, bd, dish_buf, D, 512, D_IN, 4);
    }

    // ---- 7: aggregation -> compact [rows][256] upd-input buffers ----
    int nbU = (U + 3) / 4;
    hipLaunchKernelGGL(seg_sum_both, dim3(nbU + (D + 3) / 4), dim3(256), 0, stream,
                       dish_buf + HID, user_buf + HID,
                       srcl_u, offs_u, cnt_u, srcl_d, offs_d, cnt_d,
                       user_buf, dish_buf, user_cmp, dish_cmp, U, D, nbU);

    // ---- 8: BOTH updates in one launch (bf16 A, compact lda=256) ----
    {
        int nb0 = nbU128 * 2, nb1 = nbD128 * 2;
        hipLaunchKernelGGL((mfma_gemm2<true, false, false>),
                           dim3(nb0 + nb1), dim3(256), 0, stream,
                           user_cmp, 256, Wuut, b_uu, user_upd, U, HID, HID, 2, nb0,
                           dish_cmp, 256, Wdut, b_du, dish_upd, D, HID, HID, 2);
    }

    // ---- 9: BOTH final projections in one launch (f32 out) ----
    {
        int nb0 = nbU128, nb1 = nbD128;
        hipLaunchKernelGGL((mfma_gemm2<false, false, true>),
                           dim3(nb0 + nb1), dim3(256), 0, stream,
                           user_upd, HID, Wupt, b_up, user_emb, U, OUT_D, HID, 1, nb0,
                           dish_upd, HID, Wdpt, b_dp, dish_emb, D, OUT_D, HID, 1);
    }
}